// Round 6
// baseline (462.228 us; speedup 1.0000x reference)
//
#include <hip/hip_runtime.h>
#include <hip/hip_bf16.h>

#define B_SZ 512
#define L_SZ 70
#define D_SZ 128
#define NCOL 99999           // output columns = emb rows 1..99999
#define M_ROWS (B_SZ * L_SZ) // 35840

typedef __attribute__((ext_vector_type(4))) float f32x4;
typedef __attribute__((ext_vector_type(8))) short bf16x8;
typedef __attribute__((ext_vector_type(4))) short s16x4;
typedef __attribute__((ext_vector_type(8))) unsigned short u16x8;

static __device__ __forceinline__ short f2bf(float x) {
    union { float f; unsigned u; } v; v.f = x;
    unsigned r = v.u + 0x7fffu + ((v.u >> 16) & 1u);  // RNE
    return (short)(r >> 16);
}
static __device__ __forceinline__ float bf2f(unsigned short h) {
    union { unsigned u; float f; } v; v.u = ((unsigned)h) << 16; return v.f;
}

// ---- prep: bf16 weights + fp32 transposed weights for coalesced matvecs ----
__global__ void k_prep(const float* attn_in_w, const float* w_two,
                       const float* attn_out_w, const float* w_zero,
                       const float* w_one, const float* w_trans,
                       short* Wkv, short* W2,
                       float* wqT, float* woT, float* w0T, float* w1T, float* wtT) {
    int i = blockIdx.x * 256 + threadIdx.x;   // 0 .. 32767
    if (i < 256 * 128) Wkv[i] = f2bf(attn_in_w[128 * 128 + i]);
    if (i < 128 * 128) {
        W2[i] = f2bf(w_two[i]);
        int r = i >> 7, c = i & 127;
        wqT[c * 128 + r] = attn_in_w[i];
        woT[c * 128 + r] = attn_out_w[i];
        w0T[c * 128 + r] = w_zero[i];
        w1T[c * 128 + r] = w_one[i];
    }
    if (i < 128 * 256) {                      // w_trans [128][256] -> wtT [256][128]
        int r = i >> 8, c = i & 255;
        wtT[c * 128 + r] = w_trans[i];
    }
}

// ---- fused gate + kv projection: one pass over hidden/hidden0 ----
// gate: sigma = sigmoid([h0,h].w_gate); g = h0*sig + h*(1-sig)  -> g_bf
// kv  : hidden @ [wk;wv].T + [bk;bv]                            -> kv (bf16)
__global__ void k_gatekv(const float* hidden, const float* hidden0, const float* w_gate,
                         const short* Wkv, const float* attn_in_b,
                         short* g_bf, short* kv) {
    __shared__ float wg[256];
    __shared__ short h_lds[64][136];          // bf16 hidden tile, padded rows
    int t = threadIdx.x;
    int r0 = blockIdx.x * 64;
    wg[t] = w_gate[t];
    int row = t >> 2, q = t & 3;              // 4 threads per row, interleaved chunks
    const float* hrow  = hidden  + (size_t)(r0 + row) * 128;
    const float* h0row = hidden0 + (size_t)(r0 + row) * 128;
    float h[32], h0[32];
    for (int i = 0; i < 8; i++) {             // element idx = i*16 + q*4 + j
        float4 a = *(const float4*)(hrow  + i * 16 + q * 4);
        float4 b = *(const float4*)(h0row + i * 16 + q * 4);
        h[i*4+0]=a.x; h[i*4+1]=a.y; h[i*4+2]=a.z; h[i*4+3]=a.w;
        h0[i*4+0]=b.x; h0[i*4+1]=b.y; h0[i*4+2]=b.z; h0[i*4+3]=b.w;
    }
    __syncthreads();                           // wg ready
    float p = 0.f;
    for (int i = 0; i < 8; i++)
        for (int j = 0; j < 4; j++) {
            int c = i * 16 + q * 4 + j;
            p += h0[i*4+j] * wg[c] + h[i*4+j] * wg[128 + c];
        }
    p += __shfl_xor(p, 1);
    p += __shfl_xor(p, 2);                     // sum over the 4 q-chunks of this row
    float sg = 1.f / (1.f + __expf(-p));
    float om = 1.f - sg;
    for (int i = 0; i < 8; i++) {
        s16x4 gv, hv;
        for (int j = 0; j < 4; j++) {
            gv[j] = f2bf(h0[i*4+j] * sg + h[i*4+j] * om);
            hv[j] = f2bf(h[i*4+j]);
        }
        int c = i * 16 + q * 4;
        *(s16x4*)(g_bf + (size_t)(r0 + row) * 128 + c) = gv;
        *(s16x4*)(&h_lds[row][c]) = hv;
    }
    __syncthreads();                           // h_lds ready
    // --- MFMA phase: kv = h @ Wkv^T + bias ---
    int lane = t & 63, w = t >> 6;
    int arl = lane & 15, kg = lane >> 4;
    int kbase = kg * 8;
    bf16x8 aF[4];
    for (int kk = 0; kk < 4; kk++)
        aF[kk] = *(const bf16x8*)(&h_lds[w * 16 + arl][kbase + kk * 32]);
    int cl = lane & 15;
    int rowbase = r0 + w * 16 + kg * 4;
    for (int ct = 0; ct < 16; ct++) {
        int c = ct * 16 + cl;
        f32x4 acc = {0.f, 0.f, 0.f, 0.f};
        const short* Brow = Wkv + c * 128 + kbase;
        for (int kk = 0; kk < 4; kk++) {
            bf16x8 bF = *(const bf16x8*)(Brow + kk * 32);
            acc = __builtin_amdgcn_mfma_f32_16x16x32_bf16(aF[kk], bF, acc, 0, 0, 0);
        }
        float bias = attn_in_b[128 + c];
        for (int rg = 0; rg < 4; rg++)
            kv[(size_t)(rowbase + rg) * 256 + c] = f2bf(acc[rg] + bias);
    }
}

// ---- fused: last_idx/ht0/qp + MHA (1 query) + q01 matvecs ----
// K staged as raw bf16 (19KB LDS) for occupancy.
__global__ void k_attn(const float* hidden, const int* mask, const float* s,
                       const float* wqT, const float* attn_in_b,
                       const short* kv,
                       const float* woT, const float* attn_out_b,
                       const float* w0T, const float* b_zero,
                       const float* w1T, const float* b_one,
                       float* ht0, float* q01) {
    int b = blockIdx.x, t = threadIdx.x;
    __shared__ unsigned short kp_s[L_SZ][136];
    __shared__ float s_sh[128], qp_s[128], o_s[128], ht_s[128], ht0_s[128];
    __shared__ float sc[8][72];
    __shared__ int idx_sh;
    if (t < 64) {
        int acc = 0;
        for (int l = t; l < L_SZ; l += 64) acc += mask[b * L_SZ + l];
        for (int off = 32; off; off >>= 1) acc += __shfl_down(acc, off);
        if (t == 0) {
            int idx = acc - 1;
            if (idx < 0) idx = 0;
            if (idx > L_SZ - 1) idx = L_SZ - 1;
            idx_sh = idx;
        }
    }
    s_sh[t] = s[b * 128 + t];
    const unsigned short* kvrow = (const unsigned short*)kv + (size_t)b * L_SZ * 256;
    for (int i = t; i < L_SZ * 128; i += 128) {
        int l = i >> 7, d = i & 127;
        kp_s[l][d] = kvrow[l * 256 + d];
    }
    __syncthreads();
    {
        float h0 = hidden[((size_t)b * L_SZ + idx_sh) * 128 + t];
        ht0[b * 128 + t] = h0;
        ht0_s[t] = h0;
        float acc = attn_in_b[t];
        for (int k = 0; k < 128; k++) acc += s_sh[k] * wqT[k * 128 + t];
        qp_s[t] = acc;
    }
    __syncthreads();
    for (int task = t; task < 8 * L_SZ; task += 128) {
        int h = task / L_SZ, l = task - (task / L_SZ) * L_SZ;
        const u16x8* kp = (const u16x8*)&kp_s[l][h * 16];
        u16x8 k0 = kp[0], k1 = kp[1];
        float acc = 0.f;
        for (int j = 0; j < 8; j++)
            acc += qp_s[h * 16 + j] * bf2f(k0[j]) + qp_s[h * 16 + 8 + j] * bf2f(k1[j]);
        sc[h][l] = acc * 0.25f;  // 1/sqrt(16)
    }
    __syncthreads();
    if (t < 8) {
        float m = -1e30f;
        for (int l = 0; l < L_SZ; l++) m = fmaxf(m, sc[t][l]);
        float ssum = 0.f;
        for (int l = 0; l < L_SZ; l++) { float e = __expf(sc[t][l] - m); sc[t][l] = e; ssum += e; }
        float inv = 1.f / ssum;
        for (int l = 0; l < L_SZ; l++) sc[t][l] *= inv;
    }
    __syncthreads();
    {
        int h = t >> 4;
        float acc = 0.f;
        for (int l = 0; l < L_SZ; l++) acc += sc[h][l] * bf2f(kvrow[l * 256 + 128 + t]);
        o_s[t] = acc;
    }
    __syncthreads();
    {
        float acc = attn_out_b[t];
        for (int k = 0; k < 128; k++) acc += o_s[k] * woT[k * 128 + t];
        ht_s[t] = acc;
    }
    __syncthreads();
    {
        float acc = b_one[t] + b_zero[t];
        for (int k = 0; k < 128; k++) acc += ht_s[k] * w1T[k * 128 + t] + ht0_s[k] * w0T[k * 128 + t];
        q01[b * 128 + t] = acc;
    }
}

// ---- q2 GEMM + fused alpha-logit epilogue ----
__global__ void k_gemm_q2_alpha(const short* g_bf, const short* W2, const float* b_two,
                                const float* q01, const float* w_three, float* alphaL) {
    int lane = threadIdx.x & 63, w = threadIdx.x >> 6;
    int r0 = blockIdx.x * 64 + w * 16;
    int ar = r0 + (lane & 15);
    int kbase = (lane >> 4) * 8;
    bf16x8 aF[4];
    const short* Arow = g_bf + ar * 128 + kbase;
    for (int kk = 0; kk < 4; kk++) aF[kk] = *(const bf16x8*)(Arow + kk * 32);
    float part[4][8];
    for (int r = 0; r < 4; r++)
        for (int h = 0; h < 8; h++) part[r][h] = 0.f;
    int cl = lane & 15;
    int rowbase = r0 + (lane >> 4) * 4;
    for (int ct = 0; ct < 8; ct++) {
        int c = ct * 16 + cl;
        f32x4 acc = {0.f, 0.f, 0.f, 0.f};
        const short* Brow = W2 + c * 128 + kbase;
        for (int kk = 0; kk < 4; kk++) {
            bf16x8 bF = *(const bf16x8*)(Brow + kk * 32);
            acc = __builtin_amdgcn_mfma_f32_16x16x32_bf16(aF[kk], bF, acc, 0, 0, 0);
        }
        float bias = b_two[c];
        for (int rg = 0; rg < 4; rg++) {
            int row = rowbase + rg;
            int bb = row / L_SZ;
            float val = acc[rg] + bias + q01[bb * 128 + c];
            float sg = 1.f / (1.f + __expf(-val));
            for (int h = 0; h < 8; h++) part[rg][h] += sg * w_three[h * 128 + c];
        }
    }
    for (int off = 1; off < 16; off <<= 1)
        for (int rg = 0; rg < 4; rg++)
            for (int h = 0; h < 8; h++)
                part[rg][h] += __shfl_xor(part[rg][h], off);
    if ((lane & 15) == 0) {
        for (int rg = 0; rg < 4; rg++) {
            int row = rowbase + rg;
            for (int h = 0; h < 8; h++) alphaL[row * 8 + h] = part[rg][h];
        }
    }
}

// ---- alpha softmax over L (masked) + pooling + w_trans + row-normalize ----
__global__ void k_alpha_a(const float* alphaL, const int* mask, const short* g_bf,
                          const float* ht0, const float* wtT, const float* b_trans,
                          short* a_bf) {
    int b = blockIdx.x, t = threadIdx.x;
    __shared__ float aw[L_SZ][8];
    __shared__ float mf[L_SZ];
    __shared__ float a_s[128];
    __shared__ float ht0_s[128];
    __shared__ float red[2];
    for (int i = t; i < L_SZ; i += 128) mf[i] = (float)mask[b * L_SZ + i];
    for (int i = t; i < L_SZ * 8; i += 128) aw[i >> 3][i & 7] = alphaL[b * L_SZ * 8 + i];
    ht0_s[t] = ht0[b * 128 + t];
    __syncthreads();
    if (t < 8) {
        float m = -1e30f;
        for (int l = 0; l < L_SZ; l++) {
            float v = (mf[l] == 0.f) ? -1e30f : aw[l][t];
            if (v > m) m = v;
        }
        float ssum = 0.f;
        for (int l = 0; l < L_SZ; l++) {
            float v = (mf[l] == 0.f) ? -1e30f : aw[l][t];
            float e = __expf(v - m);
            ssum += e; aw[l][t] = e;
        }
        float inv = 1.f / ssum;
        for (int l = 0; l < L_SZ; l++) aw[l][t] *= inv;
    }
    __syncthreads();
    int h = t >> 4;
    float acc = 0.f;
    const unsigned short* grow = (const unsigned short*)g_bf + b * L_SZ * 128 + t;
    for (int l = 0; l < L_SZ; l++) acc += aw[l][h] * bf2f(grow[l * 128]) * mf[l];
    a_s[t] = acc;
    __syncthreads();
    float a2 = b_trans[t];
    for (int k = 0; k < 128; k++)
        a2 += a_s[k] * wtT[k * 128 + t] + ht0_s[k] * wtT[(128 + k) * 128 + t];
    float sq = a2 * a2;
    for (int off = 32; off; off >>= 1) sq += __shfl_down(sq, off);
    if ((t & 63) == 0) red[t >> 6] = sq;
    __syncthreads();
    float nrm = sqrtf(red[0] + red[1]) + 1e-12f;
    a_bf[b * 128 + t] = f2bf(a2 / nrm);
}

// ---- final: out = 12 * a_norm @ (emb[1:]/||.||).T   (M=512, N=99999, K=128)
// BARRIER-FREE: per-wave private LDS staging (same-wave DS ops are in-order);
// compiler can software-pipeline A-loads across the rt loop.
__global__ void __launch_bounds__(256, 4) k_final(const short* a_bf, const float* emb, float* out) {
    __shared__ float cbuf[4][16][36];          // per-wave [16 rows][32 cols + pad]
    int t = threadIdx.x;
    int lane = t & 63, w = t >> 6;
    int bx = blockIdx.x;
    int cl = lane & 15, kg = lane >> 4;
    int kbase = kg * 8;

    // --- build B fragments for 2 col-tiles, with fused normalization ---
    bf16x8 bF[2][4];
    for (int ct2 = 0; ct2 < 2; ct2++) {
        int c0 = bx * 128 + w * 32 + ct2 * 16 + cl;   // output col
        float x[4][8];
        float ss = 0.f;
        if (c0 < NCOL) {
            const float* e = emb + (size_t)(c0 + 1) * 128 + kbase;
            for (int kk = 0; kk < 4; kk++) {
                float4 v0 = *(const float4*)(e + kk * 32);
                float4 v1 = *(const float4*)(e + kk * 32 + 4);
                x[kk][0] = v0.x; x[kk][1] = v0.y; x[kk][2] = v0.z; x[kk][3] = v0.w;
                x[kk][4] = v1.x; x[kk][5] = v1.y; x[kk][6] = v1.z; x[kk][7] = v1.w;
                for (int j = 0; j < 8; j++) ss += x[kk][j] * x[kk][j];
            }
        } else {
            for (int kk = 0; kk < 4; kk++)
                for (int j = 0; j < 8; j++) x[kk][j] = 0.f;
        }
        ss += __shfl_xor(ss, 16);
        ss += __shfl_xor(ss, 32);          // full-column sum across the 4 k-groups
        float inv = 1.f / (sqrtf(ss) + 1e-12f);
        for (int kk = 0; kk < 4; kk++) {
            bf16x8 f;
            for (int j = 0; j < 8; j++) f[j] = f2bf(x[kk][j] * inv);
            bF[ct2][kk] = f;
        }
    }

    int cend = NCOL - bx * 128;
    if (cend > 128) cend = 128;
    int srow = lane >> 2, schunk = lane & 3;   // store mapping: 4 lanes per row
    int scb = w * 32 + schunk * 8;             // col base within block tile

    for (int rt = 0; rt < 32; rt++) {
        bf16x8 aF[4];
        const short* Arow = a_bf + (size_t)(rt * 16 + cl) * 128 + kbase;
        for (int kk = 0; kk < 4; kk++) aF[kk] = *(const bf16x8*)(Arow + kk * 32);
        f32x4 acc0 = {0.f, 0.f, 0.f, 0.f}, acc1 = {0.f, 0.f, 0.f, 0.f};
        for (int kk = 0; kk < 4; kk++) {
            acc0 = __builtin_amdgcn_mfma_f32_16x16x32_bf16(aF[kk], bF[0][kk], acc0, 0, 0, 0);
            acc1 = __builtin_amdgcn_mfma_f32_16x16x32_bf16(aF[kk], bF[1][kk], acc1, 0, 0, 0);
        }
        // per-wave transpose staging (no block barrier needed)
        for (int rg = 0; rg < 4; rg++) {
            cbuf[w][kg * 4 + rg][cl]      = 12.f * acc0[rg];
            cbuf[w][kg * 4 + rg][16 + cl] = 12.f * acc1[rg];
        }
        asm volatile("s_waitcnt lgkmcnt(0)" ::: "memory");   // writes visible to wave
        f32x4 v0 = *(const f32x4*)&cbuf[w][srow][schunk * 8];
        f32x4 v1 = *(const f32x4*)&cbuf[w][srow][schunk * 8 + 4];
        asm volatile("s_waitcnt lgkmcnt(0)" ::: "memory");   // reads done before next writes
        size_t gr = (size_t)(rt * 16 + srow) * NCOL + (size_t)bx * 128 + scb;
        if (scb + 7 < cend) {
            *(f32x4*)(out + gr) = v0;
            *(f32x4*)(out + gr + 4) = v1;
        } else {
            for (int j = 0; j < 4; j++) if (scb + j < cend) out[gr + j] = v0[j];
            for (int j = 0; j < 4; j++) if (scb + 4 + j < cend) out[gr + 4 + j] = v1[j];
        }
    }
}

extern "C" void kernel_launch(void* const* d_in, const int* in_sizes, int n_in,
                              void* d_out, int out_size, void* d_ws, size_t ws_size,
                              hipStream_t stream) {
    const float* hidden     = (const float*)d_in[0];
    const float* hidden0    = (const float*)d_in[1];
    const int*   mask       = (const int*)d_in[2];
    const float* s          = (const float*)d_in[3];
    const float* emb        = (const float*)d_in[4];
    const float* attn_in_w  = (const float*)d_in[5];
    const float* attn_in_b  = (const float*)d_in[6];
    const float* attn_out_w = (const float*)d_in[7];
    const float* attn_out_b = (const float*)d_in[8];
    const float* w_zero     = (const float*)d_in[9];
    const float* b_zero     = (const float*)d_in[10];
    const float* w_one      = (const float*)d_in[11];
    const float* b_one      = (const float*)d_in[12];
    const float* w_two      = (const float*)d_in[13];
    const float* b_two      = (const float*)d_in[14];
    const float* w_three    = (const float*)d_in[15];
    const float* w_gate     = (const float*)d_in[16];
    const float* w_trans    = (const float*)d_in[17];
    const float* b_trans    = (const float*)d_in[18];
    float* out = (float*)d_out;

    char* p = (char*)d_ws;
    float* ht0    = (float*)p; p += (size_t)B_SZ * 128 * 4;
    float* q01    = (float*)p; p += (size_t)B_SZ * 128 * 4;
    float* alphaL = (float*)p; p += (size_t)B_SZ * L_SZ * 8 * 4;
    short* a_bf   = (short*)p; p += (size_t)B_SZ * 128 * 2;
    short* Wkv    = (short*)p; p += (size_t)256 * 128 * 2;
    short* W2     = (short*)p; p += (size_t)128 * 128 * 2;
    float* wqT    = (float*)p; p += (size_t)128 * 128 * 4;
    float* woT    = (float*)p; p += (size_t)128 * 128 * 4;
    float* w0T    = (float*)p; p += (size_t)128 * 128 * 4;
    float* w1T    = (float*)p; p += (size_t)128 * 128 * 4;
    float* wtT    = (float*)p; p += (size_t)256 * 128 * 4;
    short* g_bf   = (short*)p; p += (size_t)M_ROWS * 128 * 2;
    short* kv     = (short*)p; p += (size_t)M_ROWS * 256 * 2;

    k_prep<<<128, 256, 0, stream>>>(attn_in_w, w_two, attn_out_w, w_zero, w_one, w_trans,
                                    Wkv, W2, wqT, woT, w0T, w1T, wtT);
    k_gatekv<<<M_ROWS / 64, 256, 0, stream>>>(hidden, hidden0, w_gate, Wkv, attn_in_b,
                                              g_bf, kv);
    k_attn<<<B_SZ, 128, 0, stream>>>(hidden, mask, s, wqT, attn_in_b, kv,
                                     woT, attn_out_b, w0T, b_zero, w1T, b_one, ht0, q01);
    k_gemm_q2_alpha<<<M_ROWS / 64, 256, 0, stream>>>(g_bf, W2, b_two, q01, w_three, alphaL);
    k_alpha_a<<<B_SZ, 128, 0, stream>>>(alphaL, mask, g_bf, ht0, wtT, b_trans, a_bf);
    k_final<<<(NCOL + 127) / 128, 256, 0, stream>>>(a_bf, emb, out);
}

// Round 7
// 437.795 us; speedup vs baseline: 1.0558x; 1.0558x over previous
//
#include <hip/hip_runtime.h>
#include <hip/hip_bf16.h>

#define B_SZ 512
#define L_SZ 70
#define D_SZ 128
#define NCOL 99999           // output columns = emb rows 1..99999
#define HPAD 152             // shorts per LDS row (304B = 19*16B, odd 16B-stride)

typedef __attribute__((ext_vector_type(4))) float f32x4;
typedef __attribute__((ext_vector_type(8))) short bf16x8;
typedef __attribute__((ext_vector_type(4))) short s16x4;
typedef __attribute__((ext_vector_type(8))) unsigned short u16x8;

static __device__ __forceinline__ short f2bf(float x) {
    union { float f; unsigned u; } v; v.f = x;
    unsigned r = v.u + 0x7fffu + ((v.u >> 16) & 1u);  // RNE
    return (short)(r >> 16);
}
static __device__ __forceinline__ float bf2f(unsigned short h) {
    union { unsigned u; float f; } v; v.u = ((unsigned)h) << 16; return v.f;
}

// ---- prep: bf16 W2 + fp32 transposed weights for coalesced matvecs ----
__global__ void k_prep(const float* attn_in_w, const float* w_two,
                       const float* attn_out_w, const float* w_zero,
                       const float* w_one, const float* w_trans,
                       short* W2, float* wqT, float* woT, float* w0T,
                       float* w1T, float* wvT, float* wtT) {
    int i = blockIdx.x * 256 + threadIdx.x;   // 0 .. 32767
    if (i < 128 * 128) {
        W2[i] = f2bf(w_two[i]);
        int r = i >> 7, c = i & 127;
        wqT[c * 128 + r] = attn_in_w[i];                    // wq rows 0..127
        wvT[c * 128 + r] = attn_in_w[(256 + r) * 128 + c];  // wv rows 256..383
        woT[c * 128 + r] = attn_out_w[i];
        w0T[c * 128 + r] = w_zero[i];
        w1T[c * 128 + r] = w_one[i];
    }
    if (i < 128 * 256) {                      // w_trans [128][256] -> wtT [256][128]
        int r = i >> 8, c = i & 255;
        wtT[c * 128 + r] = w_trans[i];
    }
}

// ---- per-batch megakernel: gate + (z-trick) MHA + q01 + q2/alpha + pool + norm ----
__global__ void __launch_bounds__(256, 2)
k_mega(const float* hidden, const float* hidden0, const int* mask, const float* s,
       const float* attn_in_w, const float* attn_in_b, const float* attn_out_b,
       const float* b_zero, const float* b_one,
       const short* W2, const float* b_two, const float* w_three,
       const float* w_gate,
       const float* wqT, const float* woT, const float* w0T, const float* w1T,
       const float* wvT, const float* wtT, const float* b_trans,
       short* a_bf) {
    int b = blockIdx.x, t = threadIdx.x;
    int lane = t & 63, w = t >> 6;

    __shared__ short h_lds[80][HPAD];    // bf16 hidden rows
    __shared__ short g_lds[80][HPAD];    // bf16 gated rows
    __shared__ float zp[8][128];         // z (scores) then p (pooled V)
    __shared__ float sc_al[80][8];       // MHA scores -> alpha logits/weights
    __shared__ float wg_sh[256];
    __shared__ float bufA[128];          // s -> o
    __shared__ float bufB[128];          // qp -> ht -> a
    __shared__ float ht0_f[128], q01_s[128];
    __shared__ float ch[8], mf[80], red[2];
    __shared__ int idx_sh;

    // ---- ph0: preload ----
    wg_sh[t] = w_gate[t];
    if (t >= 128) bufA[t - 128] = s[(size_t)b * 128 + (t - 128)];
    if (t < 70) mf[t] = (float)mask[b * L_SZ + t];
    for (int i = t; i < 10 * HPAD; i += 256) g_lds[70 + i / HPAD][i % HPAD] = 0;
    __syncthreads();

    // ---- ph1: gate + h/g to LDS (bf16); t==0 computes last_idx ----
    for (int lb = 0; lb < L_SZ; lb += 64) {
        int l = lb + (t >> 2), q = t & 3;
        if (l < L_SZ) {
            const float* hr  = hidden  + ((size_t)b * L_SZ + l) * 128 + q * 32;
            const float* h0r = hidden0 + ((size_t)b * L_SZ + l) * 128 + q * 32;
            float4 hv4[8], h0v4[8];
            for (int i = 0; i < 8; i++) {
                hv4[i]  = *(const float4*)(hr  + i * 4);
                h0v4[i] = *(const float4*)(h0r + i * 4);
            }
            float p = 0.f;
            for (int i = 0; i < 8; i++) {
                const float* hp = (const float*)&hv4[i];
                const float* h0p = (const float*)&h0v4[i];
                for (int j = 0; j < 4; j++) {
                    int c = q * 32 + i * 4 + j;
                    p += h0p[j] * wg_sh[c] + hp[j] * wg_sh[128 + c];
                }
            }
            p += __shfl_xor(p, 1);
            p += __shfl_xor(p, 2);
            float sg = 1.f / (1.f + __expf(-p)), om = 1.f - sg;
            for (int i = 0; i < 8; i++) {
                const float* hp = (const float*)&hv4[i];
                const float* h0p = (const float*)&h0v4[i];
                s16x4 hv, gv;
                for (int j = 0; j < 4; j++) {
                    hv[j] = f2bf(hp[j]);
                    gv[j] = f2bf(h0p[j] * sg + hp[j] * om);
                }
                int c = q * 32 + i * 4;
                *(s16x4*)(&h_lds[l][c]) = hv;
                *(s16x4*)(&g_lds[l][c]) = gv;
            }
        }
    }
    if (t == 0) {
        int acc = 0;
        for (int l = 0; l < L_SZ; l++) acc += (int)mf[l];
        int idx = acc - 1;
        if (idx < 0) idx = 0;
        if (idx > L_SZ - 1) idx = L_SZ - 1;
        idx_sh = idx;
    }
    __syncthreads();

    // ---- ph3: qp = wq s + bq ; ht0 (exact fp32 from global) ----
    if (t < 128) {
        float h0 = hidden[((size_t)b * L_SZ + idx_sh) * 128 + t];
        ht0_f[t] = h0;
        float a0 = 0, a1 = 0, a2 = 0, a3 = 0;
        for (int k = 0; k < 128; k += 4) {
            a0 += bufA[k] * wqT[k * 128 + t];
            a1 += bufA[k + 1] * wqT[(k + 1) * 128 + t];
            a2 += bufA[k + 2] * wqT[(k + 2) * 128 + t];
            a3 += bufA[k + 3] * wqT[(k + 3) * 128 + t];
        }
        bufB[t] = attn_in_b[t] + ((a0 + a1) + (a2 + a3));  // qp
    }
    __syncthreads();

    // ---- ph4: z_h = wk_h^T qp_h ; ch = 0.25 * qp_h . bk_h ----
    for (int out = t; out < 1024; out += 256) {
        int h = out >> 7, d = out & 127;
        const float* wk = attn_in_w + (size_t)(128 + h * 16) * 128 + d;
        float a0 = 0, a1 = 0;
        for (int j = 0; j < 16; j += 2) {
            a0 += wk[j * 128] * bufB[h * 16 + j];
            a1 += wk[(j + 1) * 128] * bufB[h * 16 + j + 1];
        }
        zp[h][d] = a0 + a1;
    }
    if (t < 8) {
        float a = 0;
        for (int j = 0; j < 16; j++) a += bufB[t * 16 + j] * attn_in_b[128 + t * 16 + j];
        ch[t] = 0.25f * a;
    }
    __syncthreads();

    // ---- ph5: scores[l][h] = 0.25 * h_l . z_h + ch ----
    for (int task = t; task < 8 * L_SZ; task += 256) {
        int l = task % L_SZ, h = task / L_SZ;
        const u16x8* hp = (const u16x8*)&h_lds[l][0];
        float a0 = 0, a1 = 0, a2 = 0, a3 = 0;
        for (int c = 0; c < 16; c += 2) {
            u16x8 v0 = hp[c], v1 = hp[c + 1];
            for (int j = 0; j < 8; j += 2) {
                a0 += bf2f(v0[j]) * zp[h][c * 8 + j];
                a1 += bf2f(v0[j + 1]) * zp[h][c * 8 + j + 1];
                a2 += bf2f(v1[j]) * zp[h][c * 8 + 8 + j];
                a3 += bf2f(v1[j + 1]) * zp[h][c * 8 + 8 + j + 1];
            }
        }
        sc_al[l][h] = ((a0 + a1) + (a2 + a3)) * 0.25f + ch[h];
    }
    __syncthreads();

    // ---- ph6: MHA softmax over l (UNmasked, per reference) ----
    if (t < 8) {
        float m = -1e30f;
        for (int l = 0; l < L_SZ; l++) m = fmaxf(m, sc_al[l][t]);
        float ss = 0.f;
        for (int l = 0; l < L_SZ; l++) { float e = __expf(sc_al[l][t] - m); sc_al[l][t] = e; ss += e; }
        float inv = 1.f / ss;
        for (int l = 0; l < L_SZ; l++) sc_al[l][t] *= inv;
    }
    __syncthreads();

    // ---- ph7: p[h][d] = sum_l w[h,l] h_l[d] ----
    for (int out = t; out < 1024; out += 256) {
        int h = out >> 7, d = out & 127;
        float a0 = 0, a1 = 0;
        for (int l = 0; l < L_SZ; l += 2) {
            a0 += sc_al[l][h] * bf2f((unsigned short)h_lds[l][d]);
            a1 += sc_al[l + 1][h] * bf2f((unsigned short)h_lds[l + 1][d]);
        }
        zp[h][d] = a0 + a1;   // overwrite z with p (z dead)
    }
    __syncthreads();

    // ---- ph8: o[j] = bv[j] + sum_d wv[j][d] p[h(j)][d] ----
    if (t < 128) {
        int h = t >> 4;
        float a0 = 0, a1 = 0, a2 = 0, a3 = 0;
        for (int d = 0; d < 128; d += 4) {
            a0 += wvT[d * 128 + t] * zp[h][d];
            a1 += wvT[(d + 1) * 128 + t] * zp[h][d + 1];
            a2 += wvT[(d + 2) * 128 + t] * zp[h][d + 2];
            a3 += wvT[(d + 3) * 128 + t] * zp[h][d + 3];
        }
        bufA[t] = attn_in_b[256 + t] + ((a0 + a1) + (a2 + a3));  // o (s dead)
    }
    __syncthreads();

    // ---- ph9a: ht = wo o + bo ----
    if (t < 128) {
        float a0 = 0, a1 = 0, a2 = 0, a3 = 0;
        for (int k = 0; k < 128; k += 4) {
            a0 += bufA[k] * woT[k * 128 + t];
            a1 += bufA[k + 1] * woT[(k + 1) * 128 + t];
            a2 += bufA[k + 2] * woT[(k + 2) * 128 + t];
            a3 += bufA[k + 3] * woT[(k + 3) * 128 + t];
        }
        bufB[t] = attn_out_b[t] + ((a0 + a1) + (a2 + a3));  // ht (qp dead)
    }
    __syncthreads();
    // ---- ph9b: q01 = w1 ht + b1 + w0 ht0 + b0 ----
    if (t < 128) {
        float a0 = 0, a1 = 0;
        for (int k = 0; k < 128; k += 2) {
            a0 += bufB[k] * w1T[k * 128 + t] + ht0_f[k] * w0T[k * 128 + t];
            a1 += bufB[k + 1] * w1T[(k + 1) * 128 + t] + ht0_f[k + 1] * w0T[(k + 1) * 128 + t];
        }
        q01_s[t] = b_one[t] + b_zero[t] + a0 + a1;
    }
    __syncthreads();

    // ---- ph10: q2 = g @ w_two.T + b_two (MFMA) + fused alpha logits -> sc_al ----
    {
        int cl = lane & 15, kg = lane >> 4, kbase = kg * 8;
        for (int tile = w; tile < 5; tile += 4) {
            bf16x8 aF[4];
            for (int kk = 0; kk < 4; kk++)
                aF[kk] = *(const bf16x8*)(&g_lds[tile * 16 + cl][kbase + kk * 32]);
            float part[4][8];
            for (int r = 0; r < 4; r++)
                for (int h = 0; h < 8; h++) part[r][h] = 0.f;
            for (int ct = 0; ct < 8; ct++) {
                int c = ct * 16 + cl;
                f32x4 acc = {0.f, 0.f, 0.f, 0.f};
                const short* Brow = W2 + c * 128 + kbase;
                for (int kk = 0; kk < 4; kk++) {
                    bf16x8 bF = *(const bf16x8*)(Brow + kk * 32);
                    acc = __builtin_amdgcn_mfma_f32_16x16x32_bf16(aF[kk], bF, acc, 0, 0, 0);
                }
                float bias = b_two[c];
                for (int rg = 0; rg < 4; rg++) {
                    float val = acc[rg] + bias + q01_s[c];
                    float sg = 1.f / (1.f + __expf(-val));
                    for (int h = 0; h < 8; h++) part[rg][h] += sg * w_three[h * 128 + c];
                }
            }
            for (int off = 1; off < 16; off <<= 1)
                for (int rg = 0; rg < 4; rg++)
                    for (int h = 0; h < 8; h++)
                        part[rg][h] += __shfl_xor(part[rg][h], off);
            if (cl == 0) {
                for (int rg = 0; rg < 4; rg++)
                    for (int h = 0; h < 8; h++)
                        sc_al[tile * 16 + kg * 4 + rg][h] = part[rg][h];
            }
        }
    }
    __syncthreads();

    // ---- ph11a: alpha softmax over l (masked) ----
    if (t < 8) {
        float m = -1e30f;
        for (int l = 0; l < L_SZ; l++) {
            float v = (mf[l] == 0.f) ? -1e30f : sc_al[l][t];
            if (v > m) m = v;
        }
        float ss = 0.f;
        for (int l = 0; l < L_SZ; l++) {
            float v = (mf[l] == 0.f) ? -1e30f : sc_al[l][t];
            float e = __expf(v - m);
            sc_al[l][t] = e; ss += e;
        }
        float inv = 1.f / ss;
        for (int l = 0; l < L_SZ; l++) sc_al[l][t] *= inv;
    }
    __syncthreads();
    // ---- ph11b: a[d] = sum_l alpha[l,h(d)] g[l][d] mf[l] ----
    if (t < 128) {
        int h = t >> 4;
        float a0 = 0, a1 = 0;
        for (int l = 0; l < L_SZ; l += 2) {
            a0 += sc_al[l][h] * bf2f((unsigned short)g_lds[l][t]) * mf[l];
            a1 += sc_al[l + 1][h] * bf2f((unsigned short)g_lds[l + 1][t]) * mf[l + 1];
        }
        bufB[t] = a0 + a1;   // a (ht dead)
    }
    __syncthreads();

    // ---- ph12: a2 = wt [a; ht0] + bt ; normalize ; write bf16 ----
    float a2v = 0.f;
    if (t < 128) {
        float a0 = 0, a1 = 0;
        for (int k = 0; k < 128; k += 2) {
            a0 += bufB[k] * wtT[k * 128 + t] + ht0_f[k] * wtT[(128 + k) * 128 + t];
            a1 += bufB[k + 1] * wtT[(k + 1) * 128 + t] + ht0_f[k + 1] * wtT[(129 + k) * 128 + t];
        }
        a2v = b_trans[t] + a0 + a1;
        float sq = a2v * a2v;
        for (int off = 32; off; off >>= 1) sq += __shfl_down(sq, off);
        if (lane == 0) red[w] = sq;
    }
    __syncthreads();
    if (t < 128) {
        float nrm = sqrtf(red[0] + red[1]) + 1e-12f;
        a_bf[b * 128 + t] = f2bf(a2v / nrm);
    }
}

// ---- final: out = 12 * a_norm @ (emb[1:]/||.||).T   (M=512, N=99999, K=128)
// Barrier-free per-wave LDS staging; fused emb normalization.
__global__ void __launch_bounds__(256, 4) k_final(const short* a_bf, const float* emb, float* out) {
    __shared__ float cbuf[4][16][36];          // per-wave [16 rows][32 cols + pad]
    int t = threadIdx.x;
    int lane = t & 63, w = t >> 6;
    int bx = blockIdx.x;
    int cl = lane & 15, kg = lane >> 4;
    int kbase = kg * 8;

    bf16x8 bF[2][4];
    for (int ct2 = 0; ct2 < 2; ct2++) {
        int c0 = bx * 128 + w * 32 + ct2 * 16 + cl;   // output col
        float x[4][8];
        float ss = 0.f;
        if (c0 < NCOL) {
            const float* e = emb + (size_t)(c0 + 1) * 128 + kbase;
            for (int kk = 0; kk < 4; kk++) {
                float4 v0 = *(const float4*)(e + kk * 32);
                float4 v1 = *(const float4*)(e + kk * 32 + 4);
                x[kk][0] = v0.x; x[kk][1] = v0.y; x[kk][2] = v0.z; x[kk][3] = v0.w;
                x[kk][4] = v1.x; x[kk][5] = v1.y; x[kk][6] = v1.z; x[kk][7] = v1.w;
                for (int j = 0; j < 8; j++) ss += x[kk][j] * x[kk][j];
            }
        } else {
            for (int kk = 0; kk < 4; kk++)
                for (int j = 0; j < 8; j++) x[kk][j] = 0.f;
        }
        ss += __shfl_xor(ss, 16);
        ss += __shfl_xor(ss, 32);
        float inv = 1.f / (sqrtf(ss) + 1e-12f);
        for (int kk = 0; kk < 4; kk++) {
            bf16x8 f;
            for (int j = 0; j < 8; j++) f[j] = f2bf(x[kk][j] * inv);
            bF[ct2][kk] = f;
        }
    }

    int cend = NCOL - bx * 128;
    if (cend > 128) cend = 128;
    int srow = lane >> 2, schunk = lane & 3;
    int scb = w * 32 + schunk * 8;

    for (int rt = 0; rt < 32; rt++) {
        bf16x8 aF[4];
        const short* Arow = a_bf + (size_t)(rt * 16 + cl) * 128 + kbase;
        for (int kk = 0; kk < 4; kk++) aF[kk] = *(const bf16x8*)(Arow + kk * 32);
        f32x4 acc0 = {0.f, 0.f, 0.f, 0.f}, acc1 = {0.f, 0.f, 0.f, 0.f};
        for (int kk = 0; kk < 4; kk++) {
            acc0 = __builtin_amdgcn_mfma_f32_16x16x32_bf16(aF[kk], bF[0][kk], acc0, 0, 0, 0);
            acc1 = __builtin_amdgcn_mfma_f32_16x16x32_bf16(aF[kk], bF[1][kk], acc1, 0, 0, 0);
        }
        for (int rg = 0; rg < 4; rg++) {
            cbuf[w][kg * 4 + rg][cl]      = 12.f * acc0[rg];
            cbuf[w][kg * 4 + rg][16 + cl] = 12.f * acc1[rg];
        }
        asm volatile("s_waitcnt lgkmcnt(0)" ::: "memory");
        f32x4 v0 = *(const f32x4*)&cbuf[w][srow][schunk * 8];
        f32x4 v1 = *(const f32x4*)&cbuf[w][srow][schunk * 8 + 4];
        asm volatile("s_waitcnt lgkmcnt(0)" ::: "memory");
        size_t gr = (size_t)(rt * 16 + srow) * NCOL + (size_t)bx * 128 + scb;
        if (scb + 7 < cend) {
            *(f32x4*)(out + gr) = v0;
            *(f32x4*)(out + gr + 4) = v1;
        } else {
            for (int j = 0; j < 4; j++) if (scb + j < cend) out[gr + j] = v0[j];
            for (int j = 0; j < 4; j++) if (scb + 4 + j < cend) out[gr + 4 + j] = v1[j];
        }
    }
}

extern "C" void kernel_launch(void* const* d_in, const int* in_sizes, int n_in,
                              void* d_out, int out_size, void* d_ws, size_t ws_size,
                              hipStream_t stream) {
    const float* hidden     = (const float*)d_in[0];
    const float* hidden0    = (const float*)d_in[1];
    const int*   mask       = (const int*)d_in[2];
    const float* s          = (const float*)d_in[3];
    const float* emb        = (const float*)d_in[4];
    const float* attn_in_w  = (const float*)d_in[5];
    const float* attn_in_b  = (const float*)d_in[6];
    const float* attn_out_w = (const float*)d_in[7];
    const float* attn_out_b = (const float*)d_in[8];
    const float* w_zero     = (const float*)d_in[9];
    const float* b_zero     = (const float*)d_in[10];
    const float* w_one      = (const float*)d_in[11];
    const float* b_one      = (const float*)d_in[12];
    const float* w_two      = (const float*)d_in[13];
    const float* b_two      = (const float*)d_in[14];
    const float* w_three    = (const float*)d_in[15];
    const float* w_gate     = (const float*)d_in[16];
    const float* w_trans    = (const float*)d_in[17];
    const float* b_trans    = (const float*)d_in[18];
    float* out = (float*)d_out;

    char* p = (char*)d_ws;
    short* a_bf = (short*)p; p += (size_t)B_SZ * 128 * 2;
    short* W2   = (short*)p; p += (size_t)128 * 128 * 2;
    float* wqT  = (float*)p; p += (size_t)128 * 128 * 4;
    float* woT  = (float*)p; p += (size_t)128 * 128 * 4;
    float* w0T  = (float*)p; p += (size_t)128 * 128 * 4;
    float* w1T  = (float*)p; p += (size_t)128 * 128 * 4;
    float* wvT  = (float*)p; p += (size_t)128 * 128 * 4;
    float* wtT  = (float*)p; p += (size_t)256 * 128 * 4;

    k_prep<<<128, 256, 0, stream>>>(attn_in_w, w_two, attn_out_w, w_zero, w_one, w_trans,
                                    W2, wqT, woT, w0T, w1T, wvT, wtT);
    k_mega<<<B_SZ, 256, 0, stream>>>(hidden, hidden0, mask, s,
                                     attn_in_w, attn_in_b, attn_out_b,
                                     b_zero, b_one, W2, b_two, w_three, w_gate,
                                     wqT, woT, w0T, w1T, wvT, wtT, b_trans, a_bf);
    k_final<<<(NCOL + 127) / 128, 256, 0, stream>>>(a_bf, emb, out);
}